// Round 5
// baseline (349.101 us; speedup 1.0000x reference)
//
#include <hip/hip_runtime.h>
#include <hip/hip_bf16.h>

#define BB 32
#define NN 1024
#define MM 1024
#define DD 128

typedef __bf16 bf16;
typedef bf16 bf16x8 __attribute__((ext_vector_type(8)));
typedef bf16 bf16x4 __attribute__((ext_vector_type(4)));
typedef float f32x4 __attribute__((ext_vector_type(4)));

#define LOG2E 1.4426950408889634f
#define LN2   0.6931471805599453f
#define ESHIFT 30.5f
#define ESHIFT_C 5.6757e-14f   // exp(-30.5)

__device__ __forceinline__ bf16x8 ld8(const bf16* p) {
    return *reinterpret_cast<const bf16x8*>(p);
}

__device__ __forceinline__ bf16x8 cvt8(const float* p) {
    float4 a = reinterpret_cast<const float4*>(p)[0];
    float4 c = reinterpret_cast<const float4*>(p)[1];
    bf16x8 r;
    r[0]=(bf16)a.x; r[1]=(bf16)a.y; r[2]=(bf16)a.z; r[3]=(bf16)a.w;
    r[4]=(bf16)c.x; r[5]=(bf16)c.y; r[6]=(bf16)c.z; r[7]=(bf16)c.w;
    return r;
}

// ---------- fused pre-pass: coeff + Ys->bf16 + Ys^T + Xs^T ----------
// grid (80, BB): bx<16 -> coeff n-tile; bx in [16,48) -> Ys transpose tile
// (128 m x 32 d, writes Ysb + YsT); bx in [48,80) -> Xs transpose tile (XsT).
// Transposed writes are 256 B contiguous per d-row (vs 32 B before).
__global__ __launch_bounds__(256) void k_pre(
    const float* __restrict__ Xs, const float* __restrict__ Ys,
    const float* __restrict__ W, const float* __restrict__ Aw,
    const float* __restrict__ Ab, bf16* __restrict__ Xc,
    bf16* __restrict__ Ysb, bf16* __restrict__ YsT, bf16* __restrict__ XsT) {
    __shared__ float tile[128][35];
    int bx = blockIdx.x, b = blockIdx.y;
    int tid = threadIdx.x;

    if (bx < 16) {
        // ===== coeff: Xc = Xs * tanh(W @ A_w^T + A_b) =====
        int w = tid >> 6, lane = tid & 63, quad = lane >> 4, l16 = lane & 15;
        int nbase = bx * 64 + w * 16;
        f32x4 accZ[8];
#pragma unroll
        for (int ef = 0; ef < 8; ++ef) accZ[ef] = {0.f, 0.f, 0.f, 0.f};
        const float* Wb = W + ((size_t)b * NN + nbase + l16) * DD;
#pragma unroll
        for (int ks = 0; ks < 4; ++ks) {
            bf16x8 aW = cvt8(Wb + ks * 32 + quad * 8);
#pragma unroll
            for (int ef = 0; ef < 8; ++ef) {
                bf16x8 bA = cvt8(Aw + (size_t)(ef * 16 + l16) * DD + ks * 32 + quad * 8);
                accZ[ef] = __builtin_amdgcn_mfma_f32_16x16x32_bf16(aW, bA, accZ[ef], 0, 0, 0);
            }
        }
#pragma unroll
        for (int ef = 0; ef < 8; ++ef) {
            float ab = Ab[ef * 16 + l16];
#pragma unroll
            for (int r = 0; r < 4; ++r) {
                float z = accZ[ef][r] + ab;
                z = fminf(fmaxf(z, -12.f), 12.f);
                float t = __builtin_amdgcn_exp2f(z * (2.f * LOG2E));
                float c = (t - 1.f) / (t + 1.f);
                int n = nbase + quad * 4 + r;
                size_t idx = ((size_t)b * NN + n) * DD + ef * 16 + l16;
                Xc[idx] = (bf16)(Xs[idx] * c);
            }
        }
        return;
    }

    // ===== transpose sections =====
    int s = bx - 16;
    int isY = (s < 32) ? 1 : 0;
    s &= 31;
    int mtile = s >> 2, dtile = s & 3;
    int r0 = mtile * 128, d0 = dtile * 32;
    const float* src = (isY ? Ys : Xs) + (size_t)b * 1024 * DD;
#pragma unroll
    for (int p = 0; p < 4; ++p) {
        int row = p * 32 + (tid >> 3);
        int c = (tid & 7) * 4;
        float4 v = *reinterpret_cast<const float4*>(src + (size_t)(r0 + row) * DD + d0 + c);
        tile[row][c] = v.x; tile[row][c + 1] = v.y; tile[row][c + 2] = v.z; tile[row][c + 3] = v.w;
        if (isY) {
            bf16x4 o; o[0] = (bf16)v.x; o[1] = (bf16)v.y; o[2] = (bf16)v.z; o[3] = (bf16)v.w;
            *reinterpret_cast<bf16x4*>(Ysb + (size_t)b * MM * DD + (size_t)(r0 + row) * DD + d0 + c) = o;
        }
    }
    __syncthreads();
    bf16* dT = (isY ? YsT : XsT) + (size_t)b * DD * 1024;
    int dd = tid >> 3;                 // 0..31 within d-tile
    int mseg = (tid & 7) * 16;         // 16 m per thread -> 32 B contiguous
    bf16x8 o0, o1;
#pragma unroll
    for (int j = 0; j < 8; ++j) o0[j] = (bf16)tile[mseg + j][dd];
#pragma unroll
    for (int j = 0; j < 8; ++j) o1[j] = (bf16)tile[mseg + 8 + j][dd];
    *reinterpret_cast<bf16x8*>(dT + (size_t)(d0 + dd) * 1024 + r0 + mseg) = o0;
    *reinterpret_cast<bf16x8*>(dT + (size_t)(d0 + dd) * 1024 + r0 + mseg + 8) = o1;
}

// ---------- merged main, single-buffered LDS staging for 3 blocks/CU ----------
// role 0: attention_x + s (A = Xc rows, B = Ys/YsT); role 1: attention_y
// (A = Ysb rows, B = Xc/XsT). Per iteration: issue next-tile global loads into
// regs (T14), compute from the 32 KB staged tile, barrier, ds_write, barrier.
// LDS = 32 KB stage + 9 KB Et = 41 KB -> 3 blocks/CU (12 waves/CU).
__global__ __launch_bounds__(256, 3) void k_main(
    const bf16* __restrict__ Xc, const bf16* __restrict__ Ysb,
    const bf16* __restrict__ YsT, const bf16* __restrict__ XsT,
    float* __restrict__ out_x, float* __restrict__ out_y,
    float* __restrict__ out_s) {
    __shared__ __align__(16) bf16 stage[16384];      // 32 KB: [0:16K)=B, [16K:32K)=BT
    __shared__ __align__(16) bf16 Et[4][16][72];     // 9 KB, wave-private

    int L = blockIdx.x + 32 * blockIdx.y;            // 0..1023
    int xcd = L & 7, sidx = L >> 3;
    int b = xcd + 8 * (sidx & 3);                    // batch -> fixed XCD (L2 homing)
    int t = sidx >> 2;
    int role = t >> 4, tile = t & 15;
    int tid = threadIdx.x;
    int w = tid >> 6, lane = tid & 63, quad = lane >> 4, l16 = lane & 15;
    int rbase = tile * 64 + w * 16;

    const bf16* Arow  = (role == 0 ? Xc : Ysb) + ((size_t)b * 1024 + rbase + l16) * DD;
    const bf16* Bmat  = (role == 0 ? Ysb : Xc) + (size_t)b * 1024 * DD;
    const bf16* BTmat = (role == 0 ? YsT : XsT) + (size_t)b * DD * 1024;
    float* s_b = out_s + (size_t)b * NN * MM;
    float* outp = (role == 0 ? out_x : out_y);

    bf16x8 aX[4];
#pragma unroll
    for (int ks = 0; ks < 4; ++ks) aX[ks] = ld8(Arow + ks * 32 + quad * 8);

    // staging geometry: wave w owns linear bytes [w*8K, (w+1)*8K)
    int isA = (w < 2);
    uint32_t wroff[8], soff[8];
#pragma unroll
    for (int i = 0; i < 8; ++i) {
        uint32_t o = (uint32_t)(w * 8 + i) * 1024 + (uint32_t)lane * 16;
        if (isA) {                                    // B-tile rows of 256 B
            wroff[i] = o ^ (((o >> 8) & 7) << 4);
            soff[i]  = o;
        } else {                                      // BT rows of 128 B, global stride 2048 B
            uint32_t j = o - 16384;
            wroff[i] = 16384 + (j ^ (((j >> 7) & 7) << 4));
            soff[i]  = (j >> 7) * 2048 + (j & 127);
        }
    }
    const char* srcbase = (const char*)(isA ? Bmat : BTmat);
    uint32_t tstride = isA ? 16384u : 128u;

    // prologue: stage tile 0
    bf16x8 stg[8];
#pragma unroll
    for (int i = 0; i < 8; ++i)
        stg[i] = *reinterpret_cast<const bf16x8*>(srcbase + soff[i]);
#pragma unroll
    for (int i = 0; i < 8; ++i)
        *reinterpret_cast<bf16x8*>((char*)&stage[0] + wroff[i]) = stg[i];
    __syncthreads();

    f32x4 accU[8];
#pragma unroll
    for (int df = 0; df < 8; ++df) accU[df] = {0.f, 0.f, 0.f, 0.f};
    float rowsum[4] = {0.f, 0.f, 0.f, 0.f};
    uint32_t xq = (uint32_t)(l16 & 7) << 4;           // read-side swizzle term

#pragma unroll 1
    for (int tt = 0; tt < 16; ++tt) {
        // 1. issue next-tile loads; latency spans the whole compute phase
        if (tt < 15) {
#pragma unroll
            for (int i = 0; i < 8; ++i)
                stg[i] = *reinterpret_cast<const bf16x8*>(srcbase + (size_t)(tt + 1) * tstride + soff[i]);
        }
        __builtin_amdgcn_sched_barrier(0);

        const char* sb = (const char*)&stage[0];
        // 2. GEMM1: S = A @ Btile^T
        f32x4 accS[4];
#pragma unroll
        for (int mf = 0; mf < 4; ++mf) accS[mf] = {0.f, 0.f, 0.f, 0.f};
#pragma unroll
        for (int ks = 0; ks < 4; ++ks) {
            bf16x8 bY[4];
#pragma unroll
            for (int mf = 0; mf < 4; ++mf)
                bY[mf] = *reinterpret_cast<const bf16x8*>(
                    sb + (uint32_t)(mf * 16 + l16) * 256 + (((uint32_t)(ks * 64 + quad * 16)) ^ xq));
#pragma unroll
            for (int mf = 0; mf < 4; ++mf)
                accS[mf] = __builtin_amdgcn_mfma_f32_16x16x32_bf16(aX[ks], bY[mf], accS[mf], 0, 0, 0);
        }
        // 3. epilogue: E (always), softplus + s store (role 0 only)
#pragma unroll
        for (int mf = 0; mf < 4; ++mf) {
#pragma unroll
            for (int r = 0; r < 4; ++r) {
                float x = accS[mf][r];
                float E = __builtin_amdgcn_exp2f((x - ESHIFT) * LOG2E) + ESHIFT_C;
                bf16 Eb = (bf16)E;
                rowsum[r] += (float)Eb;
                Et[w][quad * 4 + r][mf * 16 + l16] = Eb;
            }
            if (role == 0) {
#pragma unroll
                for (int r = 0; r < 4; ++r) {
                    float x = accS[mf][r];
                    float ax = fabsf(x);
                    float sp = fmaxf(x, 0.f) +
                               LN2 * __builtin_amdgcn_logf(1.f + __builtin_amdgcn_exp2f(-ax * LOG2E));
                    s_b[(size_t)(rbase + quad * 4 + r) * MM + tt * 64 + mf * 16 + l16] = sp - 0.5f;
                }
            }
        }
        // 4. GEMM2: U += E @ Btile
#pragma unroll
        for (int half = 0; half < 2; ++half) {
            bf16x8 aE = *reinterpret_cast<const bf16x8*>(&Et[w][l16][half * 32 + quad * 8]);
            bf16x8 bT[8];
#pragma unroll
            for (int df = 0; df < 8; ++df)
                bT[df] = *reinterpret_cast<const bf16x8*>(
                    sb + 16384 + (uint32_t)(df * 16 + l16) * 128 + (((uint32_t)(half * 64 + quad * 16)) ^ xq));
#pragma unroll
            for (int df = 0; df < 8; ++df)
                accU[df] = __builtin_amdgcn_mfma_f32_16x16x32_bf16(aE, bT[df], accU[df], 0, 0, 0);
        }
        // 5. all reads done -> overwrite the single buffer with the next tile
        __syncthreads();
        if (tt < 15) {
#pragma unroll
            for (int i = 0; i < 8; ++i)
                *reinterpret_cast<bf16x8*>((char*)&stage[0] + wroff[i]) = stg[i];
        }
        __syncthreads();
    }

    float inv[4];
#pragma unroll
    for (int r = 0; r < 4; ++r) {
        float rs = rowsum[r];
        rs += __shfl_xor(rs, 1); rs += __shfl_xor(rs, 2);
        rs += __shfl_xor(rs, 4); rs += __shfl_xor(rs, 8);
        inv[r] = 1.f / rs;
    }
#pragma unroll
    for (int df = 0; df < 8; ++df)
#pragma unroll
        for (int r = 0; r < 4; ++r)
            outp[((size_t)b * 1024 + rbase + quad * 4 + r) * DD + df * 16 + l16] = accU[df][r] * inv[r];
}

extern "C" void kernel_launch(void* const* d_in, const int* in_sizes, int n_in,
                              void* d_out, int out_size, void* d_ws, size_t ws_size,
                              hipStream_t stream) {
    const float* Xs = (const float*)d_in[0];
    const float* Ys = (const float*)d_in[1];
    const float* W  = (const float*)d_in[2];
    const float* Aw = (const float*)d_in[3];
    const float* Ab = (const float*)d_in[4];

    char* ws = (char*)d_ws;
    bf16*  Xc     = (bf16*)(ws);                 //  8 MB
    bf16*  Ysb    = (bf16*)(ws + 8388608);       //  8 MB
    bf16*  YsT    = (bf16*)(ws + 16777216);      //  8 MB
    bf16*  XsT    = (bf16*)(ws + 25165824);      //  8 MB

    float* out_x = (float*)d_out;
    float* out_y = out_x + (size_t)BB * NN * DD;
    float* out_s = out_y + (size_t)BB * MM * DD;

    k_pre<<<dim3(80, BB), 256, 0, stream>>>(Xs, Ys, W, Aw, Ab, Xc, Ysb, YsT, XsT);
    k_main<<<dim3(32, BB), 256, 0, stream>>>(Xc, Ysb, YsT, XsT, out_x, out_y, out_s);
}

// Round 6
// 293.616 us; speedup vs baseline: 1.1890x; 1.1890x over previous
//
#include <hip/hip_runtime.h>
#include <hip/hip_bf16.h>

#define BB 32
#define NN 1024
#define MM 1024
#define DD 128

typedef __bf16 bf16;
typedef bf16 bf16x8 __attribute__((ext_vector_type(8)));
typedef bf16 bf16x4 __attribute__((ext_vector_type(4)));
typedef float f32x4 __attribute__((ext_vector_type(4)));

#define LOG2E 1.4426950408889634f
#define LN2   0.6931471805599453f
#define ESHIFT 30.5f
#define ESHIFT_C 5.6757e-14f   // exp(-30.5)

__device__ __forceinline__ bf16x8 ld8(const bf16* p) {
    return *reinterpret_cast<const bf16x8*>(p);
}

__device__ __forceinline__ bf16x8 cvt8(const float* p) {
    float4 a = reinterpret_cast<const float4*>(p)[0];
    float4 c = reinterpret_cast<const float4*>(p)[1];
    bf16x8 r;
    r[0]=(bf16)a.x; r[1]=(bf16)a.y; r[2]=(bf16)a.z; r[3]=(bf16)a.w;
    r[4]=(bf16)c.x; r[5]=(bf16)c.y; r[6]=(bf16)c.z; r[7]=(bf16)c.w;
    return r;
}

// ---------- prep: Ys->bf16 + Ys->T + Xs->T (round-4 version) ----------
__global__ void k_prep(const float* __restrict__ Xs, const float* __restrict__ Ys,
                       bf16* __restrict__ Ysb, bf16* __restrict__ YsT,
                       bf16* __restrict__ XsT) {
    __shared__ float tile[32][129];
    int b = blockIdx.y;
    int yy = blockIdx.x;
    int isY = (yy < 32);
    int r0 = (yy & 31) * 32;
    const float* s = (isY ? Ys : Xs) + (size_t)b * 1024 * DD;
    int tid = threadIdx.x;
    int c4 = (tid & 31) * 4;
#pragma unroll
    for (int p = 0; p < 4; ++p) {
        int r = p * 8 + (tid >> 5);
        float4 v = *reinterpret_cast<const float4*>(s + (size_t)(r0 + r) * DD + c4);
        tile[r][c4] = v.x; tile[r][c4 + 1] = v.y; tile[r][c4 + 2] = v.z; tile[r][c4 + 3] = v.w;
        if (isY) {
            bf16x4 o; o[0] = (bf16)v.x; o[1] = (bf16)v.y; o[2] = (bf16)v.z; o[3] = (bf16)v.w;
            *reinterpret_cast<bf16x4*>(Ysb + (size_t)b * MM * DD + (size_t)(r0 + r) * DD + c4) = o;
        }
    }
    __syncthreads();
    bf16* dT = (isY ? YsT : XsT) + (size_t)b * DD * 1024;
    int c = tid >> 1, rh = (tid & 1) * 16;
    bf16x8 o0, o1;
#pragma unroll
    for (int j = 0; j < 8; ++j) o0[j] = (bf16)tile[rh + j][c];
#pragma unroll
    for (int j = 0; j < 8; ++j) o1[j] = (bf16)tile[rh + 8 + j][c];
    *reinterpret_cast<bf16x8*>(dT + (size_t)c * 1024 + r0 + rh) = o0;
    *reinterpret_cast<bf16x8*>(dT + (size_t)c * 1024 + r0 + rh + 8) = o1;
}

// ---------- coeff: Xc = Xs * tanh(W @ A_w^T + A_b), bf16 out ----------
__global__ __launch_bounds__(256) void k_coeff(
    const float* __restrict__ Xs, const float* __restrict__ W,
    const float* __restrict__ Aw, const float* __restrict__ Ab,
    bf16* __restrict__ Xc) {
    int ntile = blockIdx.x, b = blockIdx.y;
    int tid = threadIdx.x;
    int w = tid >> 6, lane = tid & 63, quad = lane >> 4, l16 = lane & 15;
    int nbase = ntile * 64 + w * 16;

    f32x4 accZ[8];
#pragma unroll
    for (int ef = 0; ef < 8; ++ef) accZ[ef] = {0.f, 0.f, 0.f, 0.f};

    const float* Wb = W + ((size_t)b * NN + nbase + l16) * DD;
#pragma unroll
    for (int ks = 0; ks < 4; ++ks) {
        bf16x8 aW = cvt8(Wb + ks * 32 + quad * 8);
#pragma unroll
        for (int ef = 0; ef < 8; ++ef) {
            bf16x8 bA = cvt8(Aw + (size_t)(ef * 16 + l16) * DD + ks * 32 + quad * 8);
            accZ[ef] = __builtin_amdgcn_mfma_f32_16x16x32_bf16(aW, bA, accZ[ef], 0, 0, 0);
        }
    }
#pragma unroll
    for (int ef = 0; ef < 8; ++ef) {
        float ab = Ab[ef * 16 + l16];
#pragma unroll
        for (int r = 0; r < 4; ++r) {
            float z = accZ[ef][r] + ab;
            z = fminf(fmaxf(z, -12.f), 12.f);
            float t = __builtin_amdgcn_exp2f(z * (2.f * LOG2E));
            float c = (t - 1.f) / (t + 1.f);
            int n = nbase + quad * 4 + r;
            size_t idx = ((size_t)b * NN + n) * DD + ef * 16 + l16;
            Xc[idx] = (bf16)(Xs[idx] * c);
        }
    }
}

// ---------- merged main: round-4 double-buffered structure + raw barriers ----------
// ONE change vs round 4: __syncthreads() -> {sched_barrier; lgkmcnt(0); s_barrier;
// sched_barrier}. This drops the compiler's conservative vmcnt(0) drain at the
// barrier, so the 16 scattered s-stores and the prefetch loads stay in flight
// across iterations (T3/T4 counted-vmcnt idiom; compiler's own counted vmcnt
// still guards the stg ds_write data dependency).
__global__ __launch_bounds__(256, 2) void k_main(
    const bf16* __restrict__ Xc, const bf16* __restrict__ Ysb,
    const bf16* __restrict__ YsT, const bf16* __restrict__ XsT,
    float* __restrict__ out_x, float* __restrict__ out_y,
    float* __restrict__ out_s) {
    __shared__ __align__(16) bf16 stage[2][16384];   // 2 x 32 KB: [0:16K)=B, [16K:32K)=BT
    __shared__ __align__(16) bf16 Et[4][16][72];     // 9 KB, wave-private

    int L = blockIdx.x + 32 * blockIdx.y;            // 0..1023
    int xcd = L & 7, sidx = L >> 3;
    int b = xcd + 8 * (sidx & 3);                    // batch -> fixed XCD (L2 homing)
    int t = sidx >> 2;
    int role = t >> 4, tile = t & 15;
    int tid = threadIdx.x;
    int w = tid >> 6, lane = tid & 63, quad = lane >> 4, l16 = lane & 15;
    int rbase = tile * 64 + w * 16;

    const bf16* Arow  = (role == 0 ? Xc : Ysb) + ((size_t)b * 1024 + rbase + l16) * DD;
    const bf16* Bmat  = (role == 0 ? Ysb : Xc) + (size_t)b * 1024 * DD;
    const bf16* BTmat = (role == 0 ? YsT : XsT) + (size_t)b * DD * 1024;
    float* s_b = out_s + (size_t)b * NN * MM;
    float* outp = (role == 0 ? out_x : out_y);

    bf16x8 aX[4];
#pragma unroll
    for (int ks = 0; ks < 4; ++ks) aX[ks] = ld8(Arow + ks * 32 + quad * 8);

    // staging geometry: wave w owns linear bytes [w*8K, (w+1)*8K) of the 32 KB region
    int isA = (w < 2);
    uint32_t wroff[8], soff[8];
#pragma unroll
    for (int i = 0; i < 8; ++i) {
        uint32_t o = (uint32_t)(w * 8 + i) * 1024 + (uint32_t)lane * 16;
        if (isA) {                                    // B-tile rows of 256 B
            wroff[i] = o ^ (((o >> 8) & 7) << 4);
            soff[i]  = o;
        } else {                                      // BT rows of 128 B, global stride 2048 B
            uint32_t j = o - 16384;
            wroff[i] = 16384 + (j ^ (((j >> 7) & 7) << 4));
            soff[i]  = (j >> 7) * 2048 + (j & 127);
        }
    }
    const char* srcbase = (const char*)(isA ? Bmat : BTmat);
    uint32_t tstride = isA ? 16384u : 128u;

    // prologue: stage tile 0
    bf16x8 stg[8];
#pragma unroll
    for (int i = 0; i < 8; ++i)
        stg[i] = *reinterpret_cast<const bf16x8*>(srcbase + soff[i]);
#pragma unroll
    for (int i = 0; i < 8; ++i)
        *reinterpret_cast<bf16x8*>((char*)&stage[0][0] + wroff[i]) = stg[i];
    __syncthreads();

    f32x4 accU[8];
#pragma unroll
    for (int df = 0; df < 8; ++df) accU[df] = {0.f, 0.f, 0.f, 0.f};
    float rowsum[4] = {0.f, 0.f, 0.f, 0.f};
    uint32_t xq = (uint32_t)(l16 & 7) << 4;           // read-side swizzle term
    int cur = 0;

#pragma unroll 1
    for (int tt = 0; tt < 16; ++tt) {
        // 1. issue next-tile global loads (latency spans the whole compute phase)
        if (tt < 15) {
#pragma unroll
            for (int i = 0; i < 8; ++i)
                stg[i] = *reinterpret_cast<const bf16x8*>(srcbase + (size_t)(tt + 1) * tstride + soff[i]);
        }
        __builtin_amdgcn_sched_barrier(0);

        const char* sb = (const char*)&stage[cur][0];
        // 2. GEMM1: S = A @ Btile^T
        f32x4 accS[4];
#pragma unroll
        for (int mf = 0; mf < 4; ++mf) accS[mf] = {0.f, 0.f, 0.f, 0.f};
#pragma unroll
        for (int ks = 0; ks < 4; ++ks) {
            bf16x8 bY[4];
#pragma unroll
            for (int mf = 0; mf < 4; ++mf)
                bY[mf] = *reinterpret_cast<const bf16x8*>(
                    sb + (uint32_t)(mf * 16 + l16) * 256 + (((uint32_t)(ks * 64 + quad * 16)) ^ xq));
#pragma unroll
            for (int mf = 0; mf < 4; ++mf)
                accS[mf] = __builtin_amdgcn_mfma_f32_16x16x32_bf16(aX[ks], bY[mf], accS[mf], 0, 0, 0);
        }
        // 3. epilogue: E (always), softplus + s store (role 0 only)
#pragma unroll
        for (int mf = 0; mf < 4; ++mf) {
#pragma unroll
            for (int r = 0; r < 4; ++r) {
                float x = accS[mf][r];
                float E = __builtin_amdgcn_exp2f((x - ESHIFT) * LOG2E) + ESHIFT_C;
                bf16 Eb = (bf16)E;
                rowsum[r] += (float)Eb;
                Et[w][quad * 4 + r][mf * 16 + l16] = Eb;
            }
            if (role == 0) {
#pragma unroll
                for (int r = 0; r < 4; ++r) {
                    float x = accS[mf][r];
                    float ax = fabsf(x);
                    float sp = fmaxf(x, 0.f) +
                               LN2 * __builtin_amdgcn_logf(1.f + __builtin_amdgcn_exp2f(-ax * LOG2E));
                    s_b[(size_t)(rbase + quad * 4 + r) * MM + tt * 64 + mf * 16 + l16] = sp - 0.5f;
                }
            }
        }
        // 4. GEMM2: U += E @ Btile
#pragma unroll
        for (int half = 0; half < 2; ++half) {
            bf16x8 aE = *reinterpret_cast<const bf16x8*>(&Et[w][l16][half * 32 + quad * 8]);
            bf16x8 bT[8];
#pragma unroll
            for (int df = 0; df < 8; ++df)
                bT[df] = *reinterpret_cast<const bf16x8*>(
                    sb + 16384 + (uint32_t)(df * 16 + l16) * 128 + (((uint32_t)(half * 64 + quad * 16)) ^ xq));
#pragma unroll
            for (int df = 0; df < 8; ++df)
                accU[df] = __builtin_amdgcn_mfma_f32_16x16x32_bf16(aE, bT[df], accU[df], 0, 0, 0);
        }
        __builtin_amdgcn_sched_barrier(0);
        // 5. write staged tile into the other buffer
        if (tt < 15) {
#pragma unroll
            for (int i = 0; i < 8; ++i)
                *reinterpret_cast<bf16x8*>((char*)&stage[cur ^ 1][0] + wroff[i]) = stg[i];
        }
        // raw barrier: drain LDS only; global stores/loads stay in flight
        __builtin_amdgcn_sched_barrier(0);
        asm volatile("s_waitcnt lgkmcnt(0)" ::: "memory");
        __builtin_amdgcn_s_barrier();
        __builtin_amdgcn_sched_barrier(0);
        cur ^= 1;
    }

    float inv[4];
#pragma unroll
    for (int r = 0; r < 4; ++r) {
        float rs = rowsum[r];
        rs += __shfl_xor(rs, 1); rs += __shfl_xor(rs, 2);
        rs += __shfl_xor(rs, 4); rs += __shfl_xor(rs, 8);
        inv[r] = 1.f / rs;
    }
#pragma unroll
    for (int df = 0; df < 8; ++df)
#pragma unroll
        for (int r = 0; r < 4; ++r)
            outp[((size_t)b * 1024 + rbase + quad * 4 + r) * DD + df * 16 + l16] = accU[df][r] * inv[r];
}

extern "C" void kernel_launch(void* const* d_in, const int* in_sizes, int n_in,
                              void* d_out, int out_size, void* d_ws, size_t ws_size,
                              hipStream_t stream) {
    const float* Xs = (const float*)d_in[0];
    const float* Ys = (const float*)d_in[1];
    const float* W  = (const float*)d_in[2];
    const float* Aw = (const float*)d_in[3];
    const float* Ab = (const float*)d_in[4];

    char* ws = (char*)d_ws;
    bf16*  Xc     = (bf16*)(ws);                 //  8 MB
    bf16*  Ysb    = (bf16*)(ws + 8388608);       //  8 MB
    bf16*  YsT    = (bf16*)(ws + 16777216);      //  8 MB
    bf16*  XsT    = (bf16*)(ws + 25165824);      //  8 MB

    float* out_x = (float*)d_out;
    float* out_y = out_x + (size_t)BB * NN * DD;
    float* out_s = out_y + (size_t)BB * MM * DD;

    k_prep<<<dim3(64, BB), 256, 0, stream>>>(Xs, Ys, Ysb, YsT, XsT);
    k_coeff<<<dim3(NN / 64, BB), 256, 0, stream>>>(Xs, W, Aw, Ab, Xc);
    k_main<<<dim3(32, BB), 256, 0, stream>>>(Xc, Ysb, YsT, XsT, out_x, out_y, out_s);
}

// Round 7
// 279.882 us; speedup vs baseline: 1.2473x; 1.0491x over previous
//
#include <hip/hip_runtime.h>
#include <hip/hip_bf16.h>

#define BB 32
#define NN 1024
#define MM 1024
#define DD 128

typedef __bf16 bf16;
typedef bf16 bf16x8 __attribute__((ext_vector_type(8)));
typedef bf16 bf16x4 __attribute__((ext_vector_type(4)));
typedef float f32x4 __attribute__((ext_vector_type(4)));

#define LOG2E 1.4426950408889634f
#define LN2   0.6931471805599453f
#define ESHIFT 30.5f
#define ESHIFT_C 5.6757e-14f   // exp(-30.5)

__device__ __forceinline__ bf16x8 ld8(const bf16* p) {
    return *reinterpret_cast<const bf16x8*>(p);
}

__device__ __forceinline__ bf16x8 cvt8(const float* p) {
    float4 a = reinterpret_cast<const float4*>(p)[0];
    float4 c = reinterpret_cast<const float4*>(p)[1];
    bf16x8 r;
    r[0]=(bf16)a.x; r[1]=(bf16)a.y; r[2]=(bf16)a.z; r[3]=(bf16)a.w;
    r[4]=(bf16)c.x; r[5]=(bf16)c.y; r[6]=(bf16)c.z; r[7]=(bf16)c.w;
    return r;
}

// ---------- prep: Ys->bf16 + Ys^T + Xs^T, full-line transposed writes ----------
// 1D grid 2048 = 8 xcd x 4 batch x 64 tiles. Each block: one 64m x 64d tile.
// XCD-homed identically to k_main (b&7 == XCD) so writes land in the L2 that
// k_main reads them from. Transposed writes: 128 B contiguous per 8-lane group.
__global__ __launch_bounds__(256) void k_prep(
    const float* __restrict__ Xs, const float* __restrict__ Ys,
    bf16* __restrict__ Ysb, bf16* __restrict__ YsT, bf16* __restrict__ XsT) {
    __shared__ float tile[64][65];
    int L = blockIdx.x;                  // 0..2047
    int xcd = L & 7, sidx = L >> 3;
    int b = xcd + 8 * (sidx & 3);        // batch -> fixed XCD (matches k_main)
    int t = sidx >> 2;                   // 0..63
    int isY = (t < 32);
    int tt = t & 31;
    int mtile = tt >> 1, dtile = tt & 1;
    int r0 = mtile * 64, d0 = dtile * 64;
    int tid = threadIdx.x;
    const float* src = (isY ? Ys : Xs) + (size_t)b * 1024 * DD;

    int rr = tid >> 4;                   // 0..15
    int c4 = (tid & 15) * 4;             // 0..60
#pragma unroll
    for (int p = 0; p < 4; ++p) {
        int row = p * 16 + rr;
        float4 v = *reinterpret_cast<const float4*>(src + (size_t)(r0 + row) * DD + d0 + c4);
        tile[row][c4] = v.x; tile[row][c4 + 1] = v.y;
        tile[row][c4 + 2] = v.z; tile[row][c4 + 3] = v.w;
        if (isY) {
            bf16x4 o; o[0] = (bf16)v.x; o[1] = (bf16)v.y; o[2] = (bf16)v.z; o[3] = (bf16)v.w;
            *reinterpret_cast<bf16x4*>(Ysb + (size_t)b * MM * DD + (size_t)(r0 + row) * DD + d0 + c4) = o;
        }
    }
    __syncthreads();
    bf16* dT = (isY ? YsT : XsT) + (size_t)b * DD * 1024;
#pragma unroll
    for (int q = 0; q < 2; ++q) {
        int d = q * 32 + (tid >> 3);     // 0..63 within d-tile
        int m0 = (tid & 7) * 8;          // 8-lane group covers 64 m = 128 B
        bf16x8 o;
#pragma unroll
        for (int j = 0; j < 8; ++j) o[j] = (bf16)tile[m0 + j][d];
        *reinterpret_cast<bf16x8*>(dT + (size_t)(d0 + d) * 1024 + r0 + m0) = o;
    }
}

// ---------- coeff: Xc = Xs * tanh(W @ A_w^T + A_b) ----------
// MFMA part unchanged; epilogue now stages the tanh coefficients through LDS
// (bf16) so the Xs read is float4-vectorized and the Xc write is bf16x8
// (16 B/lane coalesced) instead of scalar 4 B loads / 2 B stores. XCD-homed.
__global__ __launch_bounds__(256) void k_coeff(
    const float* __restrict__ Xs, const float* __restrict__ W,
    const float* __restrict__ Aw, const float* __restrict__ Ab,
    bf16* __restrict__ Xc) {
    __shared__ bf16 cf[64][136];         // 17.4 KB coeff tile
    int L = blockIdx.x;                  // 0..511
    int xcd = L & 7, sidx = L >> 3;
    int b = xcd + 8 * (sidx & 3);
    int ntile = sidx >> 2;               // 0..15
    int tid = threadIdx.x;
    int w = tid >> 6, lane = tid & 63, quad = lane >> 4, l16 = lane & 15;
    int nbase = ntile * 64 + w * 16;

    f32x4 accZ[8];
#pragma unroll
    for (int ef = 0; ef < 8; ++ef) accZ[ef] = {0.f, 0.f, 0.f, 0.f};

    const float* Wb = W + ((size_t)b * NN + nbase + l16) * DD;
#pragma unroll
    for (int ks = 0; ks < 4; ++ks) {
        bf16x8 aW = cvt8(Wb + ks * 32 + quad * 8);
#pragma unroll
        for (int ef = 0; ef < 8; ++ef) {
            bf16x8 bA = cvt8(Aw + (size_t)(ef * 16 + l16) * DD + ks * 32 + quad * 8);
            accZ[ef] = __builtin_amdgcn_mfma_f32_16x16x32_bf16(aW, bA, accZ[ef], 0, 0, 0);
        }
    }
#pragma unroll
    for (int ef = 0; ef < 8; ++ef) {
        float ab = Ab[ef * 16 + l16];
#pragma unroll
        for (int r = 0; r < 4; ++r) {
            float z = accZ[ef][r] + ab;
            z = fminf(fmaxf(z, -12.f), 12.f);
            float t = __builtin_amdgcn_exp2f(z * (2.f * LOG2E));
            float c = (t - 1.f) / (t + 1.f);
            cf[w * 16 + quad * 4 + r][ef * 16 + l16] = (bf16)c;
        }
    }
    __syncthreads();
    // vectorized epilogue: 4 passes x (16 rows x 16 col-groups of 8)
    const float* Xs_b = Xs + ((size_t)b * NN + ntile * 64) * DD;
    bf16* Xc_b = Xc + ((size_t)b * NN + ntile * 64) * DD;
    int row = tid >> 4, colg = (tid & 15) * 8;
#pragma unroll
    for (int p = 0; p < 4; ++p) {
        int rrow = p * 16 + row;
        float4 xa = *reinterpret_cast<const float4*>(Xs_b + (size_t)rrow * DD + colg);
        float4 xb = *reinterpret_cast<const float4*>(Xs_b + (size_t)rrow * DD + colg + 4);
        bf16x8 cv = *reinterpret_cast<const bf16x8*>(&cf[rrow][colg]);
        bf16x8 o;
        o[0] = (bf16)(xa.x * (float)cv[0]); o[1] = (bf16)(xa.y * (float)cv[1]);
        o[2] = (bf16)(xa.z * (float)cv[2]); o[3] = (bf16)(xa.w * (float)cv[3]);
        o[4] = (bf16)(xb.x * (float)cv[4]); o[5] = (bf16)(xb.y * (float)cv[5]);
        o[6] = (bf16)(xb.z * (float)cv[6]); o[7] = (bf16)(xb.w * (float)cv[7]);
        *reinterpret_cast<bf16x8*>(Xc_b + (size_t)rrow * DD + colg) = o;
    }
}

// ---------- merged main: UNCHANGED from round 6 ----------
__global__ __launch_bounds__(256, 2) void k_main(
    const bf16* __restrict__ Xc, const bf16* __restrict__ Ysb,
    const bf16* __restrict__ YsT, const bf16* __restrict__ XsT,
    float* __restrict__ out_x, float* __restrict__ out_y,
    float* __restrict__ out_s) {
    __shared__ __align__(16) bf16 stage[2][16384];   // 2 x 32 KB: [0:16K)=B, [16K:32K)=BT
    __shared__ __align__(16) bf16 Et[4][16][72];     // 9 KB, wave-private

    int L = blockIdx.x + 32 * blockIdx.y;            // 0..1023
    int xcd = L & 7, sidx = L >> 3;
    int b = xcd + 8 * (sidx & 3);                    // batch -> fixed XCD (L2 homing)
    int t = sidx >> 2;
    int role = t >> 4, tile = t & 15;
    int tid = threadIdx.x;
    int w = tid >> 6, lane = tid & 63, quad = lane >> 4, l16 = lane & 15;
    int rbase = tile * 64 + w * 16;

    const bf16* Arow  = (role == 0 ? Xc : Ysb) + ((size_t)b * 1024 + rbase + l16) * DD;
    const bf16* Bmat  = (role == 0 ? Ysb : Xc) + (size_t)b * 1024 * DD;
    const bf16* BTmat = (role == 0 ? YsT : XsT) + (size_t)b * DD * 1024;
    float* s_b = out_s + (size_t)b * NN * MM;
    float* outp = (role == 0 ? out_x : out_y);

    bf16x8 aX[4];
#pragma unroll
    for (int ks = 0; ks < 4; ++ks) aX[ks] = ld8(Arow + ks * 32 + quad * 8);

    int isA = (w < 2);
    uint32_t wroff[8], soff[8];
#pragma unroll
    for (int i = 0; i < 8; ++i) {
        uint32_t o = (uint32_t)(w * 8 + i) * 1024 + (uint32_t)lane * 16;
        if (isA) {
            wroff[i] = o ^ (((o >> 8) & 7) << 4);
            soff[i]  = o;
        } else {
            uint32_t j = o - 16384;
            wroff[i] = 16384 + (j ^ (((j >> 7) & 7) << 4));
            soff[i]  = (j >> 7) * 2048 + (j & 127);
        }
    }
    const char* srcbase = (const char*)(isA ? Bmat : BTmat);
    uint32_t tstride = isA ? 16384u : 128u;

    bf16x8 stg[8];
#pragma unroll
    for (int i = 0; i < 8; ++i)
        stg[i] = *reinterpret_cast<const bf16x8*>(srcbase + soff[i]);
#pragma unroll
    for (int i = 0; i < 8; ++i)
        *reinterpret_cast<bf16x8*>((char*)&stage[0][0] + wroff[i]) = stg[i];
    __syncthreads();

    f32x4 accU[8];
#pragma unroll
    for (int df = 0; df < 8; ++df) accU[df] = {0.f, 0.f, 0.f, 0.f};
    float rowsum[4] = {0.f, 0.f, 0.f, 0.f};
    uint32_t xq = (uint32_t)(l16 & 7) << 4;
    int cur = 0;

#pragma unroll 1
    for (int tt = 0; tt < 16; ++tt) {
        if (tt < 15) {
#pragma unroll
            for (int i = 0; i < 8; ++i)
                stg[i] = *reinterpret_cast<const bf16x8*>(srcbase + (size_t)(tt + 1) * tstride + soff[i]);
        }
        __builtin_amdgcn_sched_barrier(0);

        const char* sb = (const char*)&stage[cur][0];
        f32x4 accS[4];
#pragma unroll
        for (int mf = 0; mf < 4; ++mf) accS[mf] = {0.f, 0.f, 0.f, 0.f};
#pragma unroll
        for (int ks = 0; ks < 4; ++ks) {
            bf16x8 bY[4];
#pragma unroll
            for (int mf = 0; mf < 4; ++mf)
                bY[mf] = *reinterpret_cast<const bf16x8*>(
                    sb + (uint32_t)(mf * 16 + l16) * 256 + (((uint32_t)(ks * 64 + quad * 16)) ^ xq));
#pragma unroll
            for (int mf = 0; mf < 4; ++mf)
                accS[mf] = __builtin_amdgcn_mfma_f32_16x16x32_bf16(aX[ks], bY[mf], accS[mf], 0, 0, 0);
        }
#pragma unroll
        for (int mf = 0; mf < 4; ++mf) {
#pragma unroll
            for (int r = 0; r < 4; ++r) {
                float x = accS[mf][r];
                float E = __builtin_amdgcn_exp2f((x - ESHIFT) * LOG2E) + ESHIFT_C;
                bf16 Eb = (bf16)E;
                rowsum[r] += (float)Eb;
                Et[w][quad * 4 + r][mf * 16 + l16] = Eb;
            }
            if (role == 0) {
#pragma unroll
                for (int r = 0; r < 4; ++r) {
                    float x = accS[mf][r];
                    float ax = fabsf(x);
                    float sp = fmaxf(x, 0.f) +
                               LN2 * __builtin_amdgcn_logf(1.f + __builtin_amdgcn_exp2f(-ax * LOG2E));
                    s_b[(size_t)(rbase + quad * 4 + r) * MM + tt * 64 + mf * 16 + l16] = sp - 0.5f;
                }
            }
        }
#pragma unroll
        for (int half = 0; half < 2; ++half) {
            bf16x8 aE = *reinterpret_cast<const bf16x8*>(&Et[w][l16][half * 32 + quad * 8]);
            bf16x8 bT[8];
#pragma unroll
            for (int df = 0; df < 8; ++df)
                bT[df] = *reinterpret_cast<const bf16x8*>(
                    sb + 16384 + (uint32_t)(df * 16 + l16) * 128 + (((uint32_t)(half * 64 + quad * 16)) ^ xq));
#pragma unroll
            for (int df = 0; df < 8; ++df)
                accU[df] = __builtin_amdgcn_mfma_f32_16x16x32_bf16(aE, bT[df], accU[df], 0, 0, 0);
        }
        __builtin_amdgcn_sched_barrier(0);
        if (tt < 15) {
#pragma unroll
            for (int i = 0; i < 8; ++i)
                *reinterpret_cast<bf16x8*>((char*)&stage[cur ^ 1][0] + wroff[i]) = stg[i];
        }
        __builtin_amdgcn_sched_barrier(0);
        asm volatile("s_waitcnt lgkmcnt(0)" ::: "memory");
        __builtin_amdgcn_s_barrier();
        __builtin_amdgcn_sched_barrier(0);
        cur ^= 1;
    }

    float inv[4];
#pragma unroll
    for (int r = 0; r < 4; ++r) {
        float rs = rowsum[r];
        rs += __shfl_xor(rs, 1); rs += __shfl_xor(rs, 2);
        rs += __shfl_xor(rs, 4); rs += __shfl_xor(rs, 8);
        inv[r] = 1.f / rs;
    }
#pragma unroll
    for (int df = 0; df < 8; ++df)
#pragma unroll
        for (int r = 0; r < 4; ++r)
            outp[((size_t)b * 1024 + rbase + quad * 4 + r) * DD + df * 16 + l16] = accU[df][r] * inv[r];
}

extern "C" void kernel_launch(void* const* d_in, const int* in_sizes, int n_in,
                              void* d_out, int out_size, void* d_ws, size_t ws_size,
                              hipStream_t stream) {
    const float* Xs = (const float*)d_in[0];
    const float* Ys = (const float*)d_in[1];
    const float* W  = (const float*)d_in[2];
    const float* Aw = (const float*)d_in[3];
    const float* Ab = (const float*)d_in[4];

    char* ws = (char*)d_ws;
    bf16*  Xc     = (bf16*)(ws);                 //  8 MB
    bf16*  Ysb    = (bf16*)(ws + 8388608);       //  8 MB
    bf16*  YsT    = (bf16*)(ws + 16777216);      //  8 MB
    bf16*  XsT    = (bf16*)(ws + 25165824);      //  8 MB

    float* out_x = (float*)d_out;
    float* out_y = out_x + (size_t)BB * NN * DD;
    float* out_s = out_y + (size_t)BB * MM * DD;

    k_prep<<<dim3(2048), 256, 0, stream>>>(Xs, Ys, Ysb, YsT, XsT);
    k_coeff<<<dim3(512), 256, 0, stream>>>(Xs, W, Aw, Ab, Xc);
    k_main<<<dim3(32, BB), 256, 0, stream>>>(Xc, Ysb, YsT, XsT, out_x, out_y, out_s);
}